// Round 5
// baseline (74.026 us; speedup 1.0000x reference)
//
#include <hip/hip_runtime.h>
#include <hip/hip_bf16.h>
#include <hip/hip_cooperative_groups.h>

namespace cg = cooperative_groups;

// SlotModel: B=2048, L=512, H=64, VOCAB=64, k=6 slots.
// h[b,l] depends only on token id (64 values) -> 64-entry tables + per-batch
// rank-based top-6. SINGLE cooperative dispatch: blocks 0..63 produce table
// rows (one token each), grid.sync() (ROCm's validated cross-XCD barrier —
// round-4's hand-rolled atomic spin stalled 155us on XCD visibility), then all
// 512 blocks consume with plain loads. No cross-replay state.

#define LSEQ 512
#define BODY 509       // L-3 positions eligible for slots
#define KSLOTS 6
#define INF_KEY 0x7FFFFFFF

__device__ __forceinline__ float wsum(float x) {
#pragma unroll
  for (int off = 32; off >= 1; off >>= 1) x += __shfl_xor(x, off, 64);
  return x;
}

// Dtype probe: first 256 ushorts of embed (512B). True bf16 embed ~N(0,0.02^2)
// -> exponent < 127. If really f32, the 128 low-mantissa halves have ~random
// exponent bits -> some exp>=127 w.p. 1-2^-128. Grid-uniform result.
__device__ __forceinline__ bool probe_bf16(const void* embed) {
  const ushort* e = (const ushort*)embed;
  const int lane = threadIdx.x & 63;
  bool bad = false;
#pragma unroll
  for (int i = 0; i < 4; ++i) {
    const int exp = (e[lane * 4 + i] >> 7) & 0xFF;
    if (exp >= 127) bad = true;
  }
  return !__any(bad);
}

template <bool BF>
__device__ __forceinline__ float ldel(const void* p, int i) {
  if (BF) return __bfloat162float(((const __hip_bfloat16*)p)[i]);
  return ((const float*)p)[i];
}

template <bool BF>
__device__ void fused_body(const int* seq, const void* embed, const void* W1,
                           const void* b1, const void* W2, const void* b2,
                           const void* gamma, const void* beta, const void* Wq,
                           const void* bq, const void* Wo, const void* bo,
                           float* h_table, float* norm_table, float* q_table,
                           float* out_table, void* out) {
  const int tid = threadIdx.x;
  const int wave = tid >> 6, lane = tid & 63;
  const int b = blockIdx.x * 4 + wave;
  const int* srow = seq + b * LSEQ;
  // Prefetch this wave's seq row (held in registers across the barrier).
  const int4 s0 = *(const int4*)(srow + 8 * lane);
  const int4 s1 = *(const int4*)(srow + 8 * lane + 4);

  // ---- producer: blocks 0..63, one token each ----
  if (blockIdx.x < 64) {
    const int v = blockIdx.x;
    __shared__ float e_s[64];
    __shared__ float h1_s[128];
    __shared__ float h_s[64];
    if (tid < 64) e_s[tid] = ldel<BF>(embed, v * 64 + tid);
    __syncthreads();
    if (tid < 128) {  // layer 1: one output per thread, coalesced W1
      float a = ldel<BF>(b1, tid);
#pragma unroll
      for (int k = 0; k < 64; ++k) a += e_s[k] * ldel<BF>(W1, k * 128 + tid);
      h1_s[tid] = fmaxf(a, 0.f);
    }
    __syncthreads();
    if (tid < 64) {  // layer 2 + LayerNorm (wave 0 only -> wsum valid)
      float f = ldel<BF>(b2, tid);
#pragma unroll
      for (int j = 0; j < 128; ++j) f += h1_s[j] * ldel<BF>(W2, j * 64 + tid);
      const float x = e_s[tid] + f;
      const float mu = wsum(x) * (1.f / 64.f);
      const float d = x - mu;
      const float var = wsum(d * d) * (1.f / 64.f);
      const float h =
          d / sqrtf(var + 1e-5f) * ldel<BF>(gamma, tid) + ldel<BF>(beta, tid);
      h_s[tid] = h;
      h_table[v * 64 + tid] = h;
      const float n2 = wsum(h * h);
      if (tid == 0) norm_table[v] = sqrtf(n2);
    }
    __syncthreads();
    if (tid < 128) {  // q row (h@Wq+bq) and out row (h@Wo+bo; bo folded)
      const int c = tid & 63;
      const bool isq = tid < 64;
      float acc = isq ? ldel<BF>(bq, c) : ldel<BF>(bo, c);
      const void* W = isq ? Wq : Wo;
#pragma unroll
      for (int i = 0; i < 64; ++i) acc += h_s[i] * ldel<BF>(W, i * 64 + c);
      if (isq) q_table[v * 64 + c] = acc;
      else     out_table[v * 64 + c] = acc;
    }
  }

  // ---- grid-wide barrier: producer writes become visible everywhere ----
  cg::this_grid().sync();

  // ---- consumer: all 512 blocks, 4 batch rows each (one per wave) ----
  // ranks per-wave via shfl (no LDS, no barriers): rank of token `lane`
  const float nv = norm_table[lane];
  int r = 0;
#pragma unroll
  for (int u = 0; u < 64; ++u) {
    const float nu = __shfl(nv, u, 64);
    r += (nu > nv) ? 1 : 0;  // ties share rank -> stable-by-position
  }

  const int vals[8] = {s0.x, s0.y, s0.z, s0.w, s1.x, s1.y, s1.z, s1.w};
  int keys[8];
#pragma unroll
  for (int i = 0; i < 8; ++i) {
    const int p = 8 * lane + i;
    const int rk = __shfl(r, vals[i], 64);
    keys[i] = (p < BODY) ? ((rk << 15) | (p << 6) | vals[i]) : INF_KEY;
  }
  const int v_last = __shfl(vals[7], 63, 64);  // srow[511]

  int winner[KSLOTS];
#pragma unroll
  for (int s = 0; s < KSLOTS; ++s) {
    int lmin = keys[0];
#pragma unroll
    for (int i = 1; i < 8; ++i) lmin = min(lmin, keys[i]);
    int gmin = lmin;
#pragma unroll
    for (int off = 32; off >= 1; off >>= 1)
      gmin = min(gmin, __shfl_xor(gmin, off, 64));
    winner[s] = gmin;
    if (lmin == gmin) {  // keys unique (pos field) -> exactly one match
#pragma unroll
      for (int i = 0; i < 8; ++i)
        if (keys[i] == gmin) keys[i] = INF_KEY;
    }
  }

  const float qv = q_table[v_last * 64 + lane];
  float sc[KSLOTS];
#pragma unroll
  for (int s = 0; s < KSLOTS; ++s)
    sc[s] = wsum(qv * h_table[(winner[s] & 63) * 64 + lane]) * 0.125f;
  float m = sc[0];
#pragma unroll
  for (int s = 1; s < KSLOTS; ++s) m = fmaxf(m, sc[s]);
  float ex[KSLOTS], sum = 0.f;
#pragma unroll
  for (int s = 0; s < KSLOTS; ++s) {
    ex[s] = expf(sc[s] - m);
    sum += ex[s];
  }
  const float inv = 1.f / sum;
  float acc = 0.f;
#pragma unroll
  for (int s = 0; s < KSLOTS; ++s)
    acc += (ex[s] * inv) * out_table[(winner[s] & 63) * 64 + lane];

  if (BF) ((__hip_bfloat16*)out)[b * 64 + lane] = __float2bfloat16(acc);
  else    ((float*)out)[b * 64 + lane] = acc;
}

__global__ __launch_bounds__(256) void k_fused(
    const int* seq, const void* embed, const void* W1, const void* b1,
    const void* W2, const void* b2, const void* gamma, const void* beta,
    const void* Wq, const void* bq, const void* Wo, const void* bo,
    float* h_table, float* norm_table, float* q_table, float* out_table,
    void* out) {
  if (probe_bf16(embed))  // grid-uniform branch (same data everywhere)
    fused_body<true>(seq, embed, W1, b1, W2, b2, gamma, beta, Wq, bq, Wo, bo,
                     h_table, norm_table, q_table, out_table, out);
  else
    fused_body<false>(seq, embed, W1, b1, W2, b2, gamma, beta, Wq, bq, Wo, bo,
                      h_table, norm_table, q_table, out_table, out);
}

extern "C" void kernel_launch(void* const* d_in, const int* in_sizes, int n_in,
                              void* d_out, int out_size, void* d_ws, size_t ws_size,
                              hipStream_t stream) {
  const int* seq    = (const int*)d_in[0];
  const void* embed = d_in[1];
  const void* W1    = d_in[2];
  const void* b1    = d_in[3];
  const void* W2    = d_in[4];
  const void* b2    = d_in[5];
  const void* gamma = d_in[6];
  const void* beta  = d_in[7];
  const void* Wq    = d_in[8];
  const void* bq    = d_in[9];
  const void* Wo    = d_in[10];
  const void* bo    = d_in[11];

  float* ws         = (float*)d_ws;
  float* h_table    = ws;          // 4096 f32
  float* norm_table = ws + 4096;   // 64 f32
  float* q_table    = ws + 4224;   // 4096 f32
  float* out_table  = ws + 8320;   // 4096 f32
  void*  outp       = d_out;

  void* args[] = {(void*)&seq, (void*)&embed, (void*)&W1, (void*)&b1,
                  (void*)&W2,  (void*)&b2,    (void*)&gamma, (void*)&beta,
                  (void*)&Wq,  (void*)&bq,    (void*)&Wo,  (void*)&bo,
                  (void*)&h_table, (void*)&norm_table, (void*)&q_table,
                  (void*)&out_table, (void*)&outp};
  hipLaunchCooperativeKernel((void*)k_fused, dim3(512), dim3(256), args, 0,
                             stream);
}

// Round 6
// 41.021 us; speedup vs baseline: 1.8046x; 1.8046x over previous
//
#include <hip/hip_runtime.h>
#include <hip/hip_bf16.h>

// SlotModel: B=2048, L=512, H=64, VOCAB=64, k=6 slots.
// h[b,l] depends only on token id -> 64-entry h/norm tables.
// Round 4/5 lesson (measured): cross-block handoff costs 50-150us on MI355X
// (atomic spin 155us, grid.sync 55us) — worse than a dispatch (~8.8us).
// This round: ONE plain dispatch, EVERY block redundantly computes h+norms
// (1M FMA = ~3.4us/block, parallel, zero communication), then consumes its
// own 8 batch rows. q/out projections are done per-row via readlane loops
// (out = sum_i ctx[i]*Wo[i,:] + bo), so no q/out tables exist at all.

#define LSEQ 512
#define BODY 509       // L-3 positions eligible for slots
#define KSLOTS 6
#define INF_KEY 0x7FFFFFFF
#define PAD 68         // LDS row stride (dwords): 16B-aligned, banks spread

__device__ __forceinline__ float wsum(float x) {
#pragma unroll
  for (int off = 32; off >= 1; off >>= 1) x += __shfl_xor(x, off, 64);
  return x;
}

// Dtype probe: first 256 ushorts of embed (512B). True bf16 embed ~N(0,0.02^2)
// -> exponent < 127. If really f32, the 128 low-mantissa halves have ~random
// exponent bits -> some exp>=127 w.p. 1-2^-128. Grid-uniform result.
__device__ __forceinline__ bool probe_bf16(const void* embed) {
  const ushort* e = (const ushort*)embed;
  const int lane = threadIdx.x & 63;
  bool bad = false;
#pragma unroll
  for (int i = 0; i < 4; ++i) {
    const int exp = (e[lane * 4 + i] >> 7) & 0xFF;
    if (exp >= 127) bad = true;
  }
  return !__any(bad);
}

template <bool BF>
__device__ __forceinline__ float ldel(const void* p, int i) {
  if (BF) return __bfloat162float(((const __hip_bfloat16*)p)[i]);
  return ((const float*)p)[i];
}

template <bool BF>
__device__ void fused_body(const int* __restrict__ seq, const void* embed,
                           const void* W1, const void* b1, const void* W2,
                           const void* b2, const void* gamma, const void* beta,
                           const void* Wq, const void* bq, const void* Wo,
                           const void* bo, void* out) {
  __shared__ float s_et[64 * PAD];    // e_t[k][v]  = embed[v][k]
  __shared__ float s_h1[128 * PAD];   // h1_t[c][v] = relu fc1 out
  __shared__ float s_ht[64 * PAD];    // h_t[t][v]  = h[v][t]
  __shared__ float s_norm[64];

  const int tid = threadIdx.x;
  const int wave = tid >> 6, lane = tid & 63;

  // --- prefetch this wave's 2 seq rows (latency hides under producer) ---
  const int row0 = blockIdx.x * 8 + wave * 2;
  const int4 a0 = *(const int4*)(seq + row0 * LSEQ + 8 * lane);
  const int4 a1 = *(const int4*)(seq + row0 * LSEQ + 8 * lane + 4);
  const int4 c0 = *(const int4*)(seq + (row0 + 1) * LSEQ + 8 * lane);
  const int4 c1 = *(const int4*)(seq + (row0 + 1) * LSEQ + 8 * lane + 4);

  // ---- P1: embed -> LDS transposed ----
  {
    const int v = tid >> 2;               // 16 elements of one token row
    const int k0 = (tid & 3) * 16;
#pragma unroll
    for (int j = 0; j < 16; ++j)
      s_et[(k0 + j) * PAD + v] = ldel<BF>(embed, v * 64 + k0 + j);
  }
  __syncthreads();

  // ---- P2: layer 1 (relu(E@W1+b1)), thread = (col c, 32 tokens) ----
  {
    const int c = tid & 127;
    const int vb = (tid >> 7) * 32;
    float acc[32];
    const float binit = ldel<BF>(b1, c);
#pragma unroll
    for (int v = 0; v < 32; ++v) acc[v] = binit;
    for (int k = 0; k < 64; ++k) {
      const float w = ldel<BF>(W1, k * 128 + c);
      const float4* ep = (const float4*)&s_et[k * PAD + vb];
#pragma unroll
      for (int j = 0; j < 8; ++j) {
        const float4 e4 = ep[j];
        acc[4 * j + 0] += e4.x * w;
        acc[4 * j + 1] += e4.y * w;
        acc[4 * j + 2] += e4.z * w;
        acc[4 * j + 3] += e4.w * w;
      }
    }
#pragma unroll
    for (int v = 0; v < 32; ++v) s_h1[c * PAD + vb + v] = fmaxf(acc[v], 0.f);
  }
  __syncthreads();

  // ---- P3: layer 2 + residual + LayerNorm + norms, thread = (t, 16 tok) ----
  {
    const int t = lane;                 // dim index across the wave
    const int vb = wave * 16;
    float acc[16];
    const float b2v = ldel<BF>(b2, t);
#pragma unroll
    for (int v = 0; v < 16; ++v) acc[v] = b2v;
    for (int j = 0; j < 128; ++j) {
      const float w = ldel<BF>(W2, j * 64 + t);
      const float4* hp = (const float4*)&s_h1[j * PAD + vb];
#pragma unroll
      for (int i = 0; i < 4; ++i) {
        const float4 h4 = hp[i];
        acc[4 * i + 0] += h4.x * w;
        acc[4 * i + 1] += h4.y * w;
        acc[4 * i + 2] += h4.z * w;
        acc[4 * i + 3] += h4.w * w;
      }
    }
    const float gam = ldel<BF>(gamma, t), bet = ldel<BF>(beta, t);
#pragma unroll
    for (int v = 0; v < 16; ++v) {
      const float x = s_et[t * PAD + vb + v] + acc[v];
      const float mu = wsum(x) * (1.f / 64.f);
      const float d = x - mu;
      const float var = wsum(d * d) * (1.f / 64.f);
      const float h = d / sqrtf(var + 1e-5f) * gam + bet;
      s_ht[t * PAD + vb + v] = h;
      const float n2 = wsum(h * h);
      if (t == 0) s_norm[vb + v] = sqrtf(n2);
    }
  }
  __syncthreads();

  // ---- consumer: ranks once per wave, then 2 rows ----
  const float nv = s_norm[lane];
  int rk = 0;
#pragma unroll
  for (int u = 0; u < 64; ++u) rk += (__shfl(nv, u, 64) > nv) ? 1 : 0;

#pragma unroll
  for (int r0 = 0; r0 < 2; ++r0) {
    const int b = row0 + r0;
    const int vals[8] = {r0 ? c0.x : a0.x, r0 ? c0.y : a0.y,
                         r0 ? c0.z : a0.z, r0 ? c0.w : a0.w,
                         r0 ? c1.x : a1.x, r0 ? c1.y : a1.y,
                         r0 ? c1.z : a1.z, r0 ? c1.w : a1.w};
    int keys[8];
#pragma unroll
    for (int i = 0; i < 8; ++i) {
      const int p = 8 * lane + i;
      const int r = __shfl(rk, vals[i], 64);
      keys[i] = (p < BODY) ? ((r << 15) | (p << 6) | vals[i]) : INF_KEY;
    }
    const int v_last = __shfl(vals[7], 63, 64);  // srow[511]

    int winner[KSLOTS];
#pragma unroll
    for (int s = 0; s < KSLOTS; ++s) {
      int lmin = keys[0];
#pragma unroll
      for (int i = 1; i < 8; ++i) lmin = min(lmin, keys[i]);
      int gmin = lmin;
#pragma unroll
      for (int off = 32; off >= 1; off >>= 1)
        gmin = min(gmin, __shfl_xor(gmin, off, 64));
      winner[s] = gmin;
      if (lmin == gmin) {  // keys unique (pos field) -> exactly one match
#pragma unroll
        for (int i = 0; i < 8; ++i)
          if (keys[i] == gmin) keys[i] = INF_KEY;
      }
    }

    // q = h[v_last]@Wq + bq  (readlane broadcast + coalesced L2-hot loads)
    const float hq = s_ht[lane * PAD + v_last];
    float qv = ldel<BF>(bq, lane);
#pragma unroll
    for (int i = 0; i < 64; ++i)
      qv += __shfl(hq, i, 64) * ldel<BF>(Wq, i * 64 + lane);

    float hw[KSLOTS], sc[KSLOTS];
#pragma unroll
    for (int s = 0; s < KSLOTS; ++s) {
      hw[s] = s_ht[lane * PAD + (winner[s] & 63)];
      sc[s] = wsum(qv * hw[s]) * 0.125f;  // /sqrt(64)
    }
    float m = sc[0];
#pragma unroll
    for (int s = 1; s < KSLOTS; ++s) m = fmaxf(m, sc[s]);
    float ex[KSLOTS], sum = 0.f;
#pragma unroll
    for (int s = 0; s < KSLOTS; ++s) {
      ex[s] = expf(sc[s] - m);
      sum += ex[s];
    }
    const float inv = 1.f / sum;
    float ctx = 0.f;
#pragma unroll
    for (int s = 0; s < KSLOTS; ++s) ctx += (ex[s] * inv) * hw[s];

    // out = ctx@Wo + bo
    float o = ldel<BF>(bo, lane);
#pragma unroll
    for (int i = 0; i < 64; ++i)
      o += __shfl(ctx, i, 64) * ldel<BF>(Wo, i * 64 + lane);

    if (BF) ((__hip_bfloat16*)out)[b * 64 + lane] = __float2bfloat16(o);
    else    ((float*)out)[b * 64 + lane] = o;
  }
}

__global__ __launch_bounds__(256) void k_fused(
    const int* __restrict__ seq, const void* __restrict__ embed,
    const void* __restrict__ W1, const void* __restrict__ b1,
    const void* __restrict__ W2, const void* __restrict__ b2,
    const void* __restrict__ gamma, const void* __restrict__ beta,
    const void* __restrict__ Wq, const void* __restrict__ bq,
    const void* __restrict__ Wo, const void* __restrict__ bo,
    void* __restrict__ out) {
  if (probe_bf16(embed))
    fused_body<true>(seq, embed, W1, b1, W2, b2, gamma, beta, Wq, bq, Wo, bo,
                     out);
  else
    fused_body<false>(seq, embed, W1, b1, W2, b2, gamma, beta, Wq, bq, Wo, bo,
                      out);
}

extern "C" void kernel_launch(void* const* d_in, const int* in_sizes, int n_in,
                              void* d_out, int out_size, void* d_ws, size_t ws_size,
                              hipStream_t stream) {
  const int* seq    = (const int*)d_in[0];
  const void* embed = d_in[1];
  const void* W1    = d_in[2];
  const void* b1    = d_in[3];
  const void* W2    = d_in[4];
  const void* b2    = d_in[5];
  const void* gamma = d_in[6];
  const void* beta  = d_in[7];
  const void* Wq    = d_in[8];
  const void* bq    = d_in[9];
  const void* Wo    = d_in[10];
  const void* bo    = d_in[11];

  k_fused<<<256, 256, 0, stream>>>(seq, embed, W1, b1, W2, b2, gamma, beta,
                                   Wq, bq, Wo, bo, d_out);
}

// Round 7
// 30.398 us; speedup vs baseline: 2.4353x; 1.3495x over previous
//
#include <hip/hip_runtime.h>
#include <hip/hip_bf16.h>

// SlotModel: B=2048, L=512, H=64, VOCAB=64, k=6 slots.
// Single plain dispatch (comm-free): every block redundantly computes the
// 64-token h/norm tables (~1M FMA), then consumes 8 batch rows.
// Round-6 lesson: (a) __shared__ inside template body => LDS doubled (139KB);
// (b) tiled-LDS producer was LDS-pipe bound (4 FMA per 12-cyc b128).
// This version: lane=token, activations in LDS [c][token] (all accesses
// consecutive-lane, conflict-free b32), weights via wave-uniform loads
// (scalar path), 32 FMA per single ds_read_b32. In-lane LayerNorm.

#define LSEQ 512
#define BODY 509       // L-3 positions eligible for slots
#define KSLOTS 6
#define INF_KEY 0x7FFFFFFF

struct Smem {
  float e_col[64 * 64];   // [k][token]  e^T
  float h1[128 * 64];     // [c][token]  relu(fc1)
  float f2[64 * 64];      // [t][token]  fc2 out (pre-LN)
  float ht[64 * 65];      // [v][t]      final h, pad 65 (bank=(v+t)%32)
  float nrm[64];
};

__device__ __forceinline__ float wsum(float x) {
#pragma unroll
  for (int off = 32; off >= 1; off >>= 1) x += __shfl_xor(x, off, 64);
  return x;
}

// Dtype probe (verified rounds 2-6): first 256 ushorts of embed.
__device__ __forceinline__ bool probe_bf16(const void* embed) {
  const ushort* e = (const ushort*)embed;
  const int lane = threadIdx.x & 63;
  bool bad = false;
#pragma unroll
  for (int i = 0; i < 4; ++i) {
    const int exp = (e[lane * 4 + i] >> 7) & 0xFF;
    if (exp >= 127) bad = true;
  }
  return !__any(bad);
}

template <bool BF>
__device__ __forceinline__ float ldel(const void* p, int i) {
  if (BF) return __bfloat162float(((const __hip_bfloat16*)p)[i]);
  return ((const float*)p)[i];
}

// Pair load at element offset 2*i from a (wave-uniform) element base pointer.
template <bool BF>
__device__ __forceinline__ void ld2u(const void* p, int i, float& lo, float& hi) {
  if (BF) {
    const uint u = ((const uint*)p)[i];
    lo = __uint_as_float(u << 16);
    hi = __uint_as_float(u & 0xFFFF0000u);
  } else {
    const float2 w = ((const float2*)p)[i];
    lo = w.x;
    hi = w.y;
  }
}

template <bool BF>
__device__ __forceinline__ const void* eptr(const void* p, int elem_off) {
  return BF ? (const void*)((const ushort*)p + elem_off)
            : (const void*)((const float*)p + elem_off);
}

template <bool BF>
__device__ void fused_body(const int* __restrict__ seq, const void* embed,
                           const void* W1, const void* b1, const void* W2,
                           const void* b2, const void* gamma, const void* beta,
                           const void* Wq, const void* bq, const void* Wo,
                           const void* bo, void* out, Smem& sm) {
  const int tid = threadIdx.x;
  const int wave = tid >> 6, lane = tid & 63;

  // --- prefetch this wave's 2 seq rows (HBM latency hides under producer) ---
  const int row0 = blockIdx.x * 8 + wave * 2;
  const int4 a0 = *(const int4*)(seq + row0 * LSEQ + 8 * lane);
  const int4 a1 = *(const int4*)(seq + row0 * LSEQ + 8 * lane + 4);
  const int4 c0 = *(const int4*)(seq + (row0 + 1) * LSEQ + 8 * lane);
  const int4 c1 = *(const int4*)(seq + (row0 + 1) * LSEQ + 8 * lane + 4);

  // ---- S1: stage embed transposed -> e_col[k][v] ----
  {
    const int v = tid >> 2;
    const int k0 = (tid & 3) << 4;
#pragma unroll
    for (int j = 0; j < 16; ++j)
      sm.e_col[(k0 + j) * 64 + v] = ldel<BF>(embed, v * 64 + k0 + j);
  }
  __syncthreads();

  // ---- S2: layer 1. lane=token; wave owns cols 32w..32w+31 ----
  {
    const int cbase = __builtin_amdgcn_readfirstlane(32 * wave);
    float acc[32];
#pragma unroll
    for (int i = 0; i < 16; ++i)
      ld2u<BF>(eptr<BF>(b1, cbase), i, acc[2 * i], acc[2 * i + 1]);
#pragma unroll 4
    for (int k = 0; k < 64; ++k) {
      const float ek = sm.e_col[k * 64 + lane];          // conflict-free b32
      const void* wrow = eptr<BF>(W1, k * 128 + cbase);  // wave-uniform
#pragma unroll
      for (int i = 0; i < 16; ++i) {
        float lo, hi;
        ld2u<BF>(wrow, i, lo, hi);
        acc[2 * i] += ek * lo;
        acc[2 * i + 1] += ek * hi;
      }
    }
#pragma unroll
    for (int i = 0; i < 32; ++i)
      sm.h1[(cbase + i) * 64 + lane] = fmaxf(acc[i], 0.f);
  }
  __syncthreads();

  // ---- S3: layer 2. lane=token; wave owns cols 16w..16w+15 ----
  {
    const int cbase = __builtin_amdgcn_readfirstlane(16 * wave);
    float acc[16];
#pragma unroll
    for (int i = 0; i < 8; ++i)
      ld2u<BF>(eptr<BF>(b2, cbase), i, acc[2 * i], acc[2 * i + 1]);
#pragma unroll 4
    for (int j = 0; j < 128; ++j) {
      const float hj = sm.h1[j * 64 + lane];             // conflict-free b32
      const void* wrow = eptr<BF>(W2, j * 64 + cbase);   // wave-uniform
#pragma unroll
      for (int i = 0; i < 8; ++i) {
        float lo, hi;
        ld2u<BF>(wrow, i, lo, hi);
        acc[2 * i] += hj * lo;
        acc[2 * i + 1] += hj * hi;
      }
    }
#pragma unroll
    for (int i = 0; i < 16; ++i)
      sm.f2[(cbase + i) * 64 + lane] = acc[i];
  }
  __syncthreads();

  // ---- S4: LayerNorm + norms, in-lane (lane = token v), wave 0 only ----
  if (wave == 0) {
    float x[64];
    float s = 0.f;
#pragma unroll
    for (int t = 0; t < 64; ++t) {
      x[t] = sm.e_col[t * 64 + lane] + sm.f2[t * 64 + lane];
      s += x[t];
    }
    const float mu = s * (1.f / 64.f);
    float v2 = 0.f;
#pragma unroll
    for (int t = 0; t < 64; ++t) {
      const float d = x[t] - mu;
      v2 += d * d;
    }
    const float rstd = 1.f / sqrtf(v2 * (1.f / 64.f) + 1e-5f);
    float n2 = 0.f;
#pragma unroll
    for (int t = 0; t < 64; ++t) {
      const float h =
          (x[t] - mu) * rstd * ldel<BF>(gamma, t) + ldel<BF>(beta, t);
      sm.ht[lane * 65 + t] = h;
      n2 += h * h;
    }
    sm.nrm[lane] = sqrtf(n2);
  }
  __syncthreads();

  // ---- S5: consumer (verified in rounds 4-6), 2 rows per wave ----
  const float nv = sm.nrm[lane];
  int rk = 0;
#pragma unroll
  for (int u = 0; u < 64; ++u) rk += (__shfl(nv, u, 64) > nv) ? 1 : 0;

#pragma unroll
  for (int r0 = 0; r0 < 2; ++r0) {
    const int b = row0 + r0;
    const int vals[8] = {r0 ? c0.x : a0.x, r0 ? c0.y : a0.y,
                         r0 ? c0.z : a0.z, r0 ? c0.w : a0.w,
                         r0 ? c1.x : a1.x, r0 ? c1.y : a1.y,
                         r0 ? c1.z : a1.z, r0 ? c1.w : a1.w};
    int keys[8];
#pragma unroll
    for (int i = 0; i < 8; ++i) {
      const int p = 8 * lane + i;
      const int r = __shfl(rk, vals[i], 64);
      keys[i] = (p < BODY) ? ((r << 15) | (p << 6) | vals[i]) : INF_KEY;
    }
    const int v_last = __shfl(vals[7], 63, 64);  // srow[511]

    int winner[KSLOTS];
#pragma unroll
    for (int s = 0; s < KSLOTS; ++s) {
      int lmin = keys[0];
#pragma unroll
      for (int i = 1; i < 8; ++i) lmin = min(lmin, keys[i]);
      int gmin = lmin;
#pragma unroll
      for (int off = 32; off >= 1; off >>= 1)
        gmin = min(gmin, __shfl_xor(gmin, off, 64));
      winner[s] = gmin;
      if (lmin == gmin) {  // keys unique (pos field) -> exactly one match
#pragma unroll
        for (int i = 0; i < 8; ++i)
          if (keys[i] == gmin) keys[i] = INF_KEY;
      }
    }

    // q = h[v_last]@Wq + bq (row-uniform LDS reads; coalesced Wq loads)
    const float hq = sm.ht[v_last * 65 + lane];
    float qv = ldel<BF>(bq, lane);
#pragma unroll
    for (int i = 0; i < 64; ++i)
      qv += __shfl(hq, i, 64) * ldel<BF>(Wq, i * 64 + lane);

    float hw[KSLOTS], sc[KSLOTS];
#pragma unroll
    for (int s = 0; s < KSLOTS; ++s) {
      hw[s] = sm.ht[(winner[s] & 63) * 65 + lane];
      sc[s] = wsum(qv * hw[s]) * 0.125f;  // /sqrt(64)
    }
    float m = sc[0];
#pragma unroll
    for (int s = 1; s < KSLOTS; ++s) m = fmaxf(m, sc[s]);
    float ex[KSLOTS], sum = 0.f;
#pragma unroll
    for (int s = 0; s < KSLOTS; ++s) {
      ex[s] = expf(sc[s] - m);
      sum += ex[s];
    }
    const float inv = 1.f / sum;
    float ctx = 0.f;
#pragma unroll
    for (int s = 0; s < KSLOTS; ++s) ctx += (ex[s] * inv) * hw[s];

    // out = ctx@Wo + bo
    float o = ldel<BF>(bo, lane);
#pragma unroll
    for (int i = 0; i < 64; ++i)
      o += __shfl(ctx, i, 64) * ldel<BF>(Wo, i * 64 + lane);

    if (BF) ((__hip_bfloat16*)out)[b * 64 + lane] = __float2bfloat16(o);
    else    ((float*)out)[b * 64 + lane] = o;
  }
}

__global__ __launch_bounds__(256) void k_fused(
    const int* __restrict__ seq, const void* __restrict__ embed,
    const void* __restrict__ W1, const void* __restrict__ b1,
    const void* __restrict__ W2, const void* __restrict__ b2,
    const void* __restrict__ gamma, const void* __restrict__ beta,
    const void* __restrict__ Wq, const void* __restrict__ bq,
    const void* __restrict__ Wo, const void* __restrict__ bo,
    void* __restrict__ out) {
  __shared__ Smem sm;  // kernel-scope: shared by both template instantiations
  if (probe_bf16(embed))
    fused_body<true>(seq, embed, W1, b1, W2, b2, gamma, beta, Wq, bq, Wo, bo,
                     out, sm);
  else
    fused_body<false>(seq, embed, W1, b1, W2, b2, gamma, beta, Wq, bq, Wo, bo,
                      out, sm);
}

extern "C" void kernel_launch(void* const* d_in, const int* in_sizes, int n_in,
                              void* d_out, int out_size, void* d_ws, size_t ws_size,
                              hipStream_t stream) {
  const int* seq    = (const int*)d_in[0];
  const void* embed = d_in[1];
  const void* W1    = d_in[2];
  const void* b1    = d_in[3];
  const void* W2    = d_in[4];
  const void* b2    = d_in[5];
  const void* gamma = d_in[6];
  const void* beta  = d_in[7];
  const void* Wq    = d_in[8];
  const void* bq    = d_in[9];
  const void* Wo    = d_in[10];
  const void* bo    = d_in[11];

  k_fused<<<256, 256, 0, stream>>>(seq, embed, W1, b1, W2, b2, gamma, beta,
                                   Wq, bq, Wo, bo, d_out);
}